// Round 2
// baseline (2921.848 us; speedup 1.0000x reference)
//
#include <hip/hip_runtime.h>

// Depthwise 3x3x3 conv (pad 1) -> InstanceNorm3d -> ReLU
// B=2, C=64, D=64, H=128, W=128. All tensors FP32 (round-1 evidence: bf16
// interpretation drove stats to NaN -> fmaxf(NaN,0)=0 -> all-zero output).

#define B_ 2
#define C_ 64
#define D_ 64
#define H_ 128
#define W_ 128

constexpr int HW  = H_ * W_;     // 16384
constexpr int DHW = D_ * HW;     // 1048576
constexpr float EPS_ = 1e-5f;
constexpr float INV_N = 1.0f / (float)DHW;

// Conv for 4 consecutive w outputs at (d, h, w0..w0+3).
__device__ __forceinline__ void conv4(const float* __restrict__ xc,
                                      const float wf[27],
                                      int d, int h, int w0, float acc[4]) {
    acc[0] = acc[1] = acc[2] = acc[3] = 0.f;
#pragma unroll
    for (int dd = 0; dd < 3; ++dd) {
        int z = d + dd - 1;
        if ((unsigned)z >= (unsigned)D_) continue;   // block-uniform branch
        const float* xz = xc + (size_t)z * HW;
#pragma unroll
        for (int dh = 0; dh < 3; ++dh) {
            int y = h + dh - 1;
            if ((unsigned)y >= (unsigned)H_) continue;
            const float* xr = xz + y * W_;
            float4 m = *(const float4*)(xr + w0);    // 16B aligned
            float lft = (w0 > 0)      ? xr[w0 - 1] : 0.f;
            float rgt = (w0 + 4 < W_) ? xr[w0 + 4] : 0.f;
            float k0 = wf[dd * 9 + dh * 3 + 0];
            float k1 = wf[dd * 9 + dh * 3 + 1];
            float k2 = wf[dd * 9 + dh * 3 + 2];
            acc[0] = fmaf(lft, k0, fmaf(m.x, k1, fmaf(m.y, k2, acc[0])));
            acc[1] = fmaf(m.x, k0, fmaf(m.y, k1, fmaf(m.z, k2, acc[1])));
            acc[2] = fmaf(m.y, k0, fmaf(m.z, k1, fmaf(m.w, k2, acc[2])));
            acc[3] = fmaf(m.z, k0, fmaf(m.w, k1, fmaf(rgt, k2, acc[3])));
        }
    }
}

__global__ void k_zero(float* __restrict__ p, int n) {
    int i = blockIdx.x * 256 + threadIdx.x;
    if (i < n) p[i] = 0.f;
}

// blockIdx.x in [0,1024): d = bx>>4, h_base = (bx&15)*8
// blockIdx.y = c, blockIdx.z = b
// thread: w0 = (tid&31)*4, h = h_base + (tid>>5)   (8 rows x 128 w = 1024 outputs)
__global__ __launch_bounds__(256) void k_stats(const float* __restrict__ x,
                                               const float* __restrict__ wgt,
                                               float* __restrict__ stats) {
    int bx = blockIdx.x;
    int c = blockIdx.y, b = blockIdx.z;
    int d = bx >> 4;
    int h0 = (bx & 15) << 3;
    int tid = threadIdx.x;
    int w0 = (tid & 31) * 4;
    int h = h0 + (tid >> 5);

    const float* xc = x + (size_t)(b * C_ + c) * DHW;
    float wf[27];
#pragma unroll
    for (int i = 0; i < 27; ++i) wf[i] = wgt[c * 27 + i];

    float acc[4];
    conv4(xc, wf, d, h, w0, acc);

    float s  = acc[0] + acc[1] + acc[2] + acc[3];
    float ss = acc[0] * acc[0] + acc[1] * acc[1] + acc[2] * acc[2] + acc[3] * acc[3];

#pragma unroll
    for (int off = 32; off; off >>= 1) {
        s  += __shfl_down(s,  off, 64);
        ss += __shfl_down(ss, off, 64);
    }
    __shared__ float ls[4], lss[4];
    int wave = tid >> 6;
    if ((tid & 63) == 0) { ls[wave] = s; lss[wave] = ss; }
    __syncthreads();
    if (tid == 0) {
        float S  = ls[0] + ls[1] + ls[2] + ls[3];
        float SS = lss[0] + lss[1] + lss[2] + lss[3];
        int bc = b * C_ + c;
        atomicAdd(&stats[2 * bc],     S);
        atomicAdd(&stats[2 * bc + 1], SS);
    }
}

__global__ __launch_bounds__(256) void k_norm(const float* __restrict__ x,
                                              const float* __restrict__ wgt,
                                              const float* __restrict__ gamma,
                                              const float* __restrict__ beta,
                                              const float* __restrict__ stats,
                                              float* __restrict__ out) {
    int bx = blockIdx.x;
    int c = blockIdx.y, b = blockIdx.z;
    int d = bx >> 4;
    int h0 = (bx & 15) << 3;
    int tid = threadIdx.x;
    int w0 = (tid & 31) * 4;
    int h = h0 + (tid >> 5);

    int bc = b * C_ + c;
    const float* xc = x + (size_t)bc * DHW;
    float wf[27];
#pragma unroll
    for (int i = 0; i < 27; ++i) wf[i] = wgt[c * 27 + i];

    float acc[4];
    conv4(xc, wf, d, h, w0, acc);

    float S = stats[2 * bc], SS = stats[2 * bc + 1];
    float mean = S * INV_N;
    float var  = SS * INV_N - mean * mean;
    float inv  = rsqrtf(var + EPS_);
    float scale = gamma[c] * inv;
    float shift = beta[c] - mean * scale;

    float4 o;
    o.x = fmaxf(fmaf(acc[0], scale, shift), 0.f);
    o.y = fmaxf(fmaf(acc[1], scale, shift), 0.f);
    o.z = fmaxf(fmaf(acc[2], scale, shift), 0.f);
    o.w = fmaxf(fmaf(acc[3], scale, shift), 0.f);

    *(float4*)(out + (size_t)bc * DHW + d * HW + h * W_ + w0) = o;
}

extern "C" void kernel_launch(void* const* d_in, const int* in_sizes, int n_in,
                              void* d_out, int out_size, void* d_ws, size_t ws_size,
                              hipStream_t stream) {
    const float* x     = (const float*)d_in[0];
    const float* wgt   = (const float*)d_in[1];
    const float* gamma = (const float*)d_in[2];
    const float* beta  = (const float*)d_in[3];
    float* out   = (float*)d_out;
    float* stats = (float*)d_ws;   // 2 * B * C floats = 1 KiB

    k_zero<<<dim3(1), dim3(256), 0, stream>>>(stats, 2 * B_ * C_);

    dim3 grid(D_ * (H_ / 8), C_, B_);   // 1024, 64, 2
    dim3 block(256);
    k_stats<<<grid, block, 0, stream>>>(x, wgt, stats);
    k_norm<<<grid, block, 0, stream>>>(x, wgt, gamma, beta, stats, out);
}